// Round 2
// baseline (151.988 us; speedup 1.0000x reference)
//
#include <hip/hip_runtime.h>
#include <math.h>

#define N       4096
#define NPARAM  15
#define BI      256      // i-rows per block (one per thread)
#define NJ      64       // j-slices
#define BJ      (N / NJ) // 64 j's per slice

// d_ws layout: X: [N][8] floats (pairwise feature sums, atomic accum) at offset 0
// X is zeroed by hipMemsetAsync before pairwise.

__device__ __forceinline__ void derive_params(const float* __restrict__ r, float* o) {
  // r -> (t, ra, dec, psi, mc, f_isco, dist, 0)
  float m1 = r[0] * 95.0f + 5.0f;
  float m2 = r[1] * 95.0f + 5.0f;
  float msum = m1 + m2;
  float mc = expf(0.6f * logf(m1 * m2) - 0.2f * logf(msum));
  o[0] = r[5];
  o[1] = r[3];
  o[2] = r[4];
  o[3] = r[7];
  o[4] = mc;
  o[5] = 220.0f / msum;
  o[6] = r[2] * 2950.0f + 50.0f;
  o[7] = 0.0f;
}

__global__ __launch_bounds__(256) void pairwise_kernel(
    const float* __restrict__ p, float* __restrict__ X) {
  __shared__ float sh[BJ * 8];   // 64 j-points x 8 derived params = 2 KB
  int ib = blockIdx.x;  // 0..15
  int jb = blockIdx.y;  // 0..63
  int t  = threadIdx.x;
  int i  = ib * BI + t;

  // stage j-slice: threads 0..63 each derive one j-point into LDS
  if (t < BJ) {
    int j = jb * BJ + t;
    float o[8];
    derive_params(p + (size_t)j * NPARAM, o);
    float4* dst = (float4*)(sh + t * 8);
    dst[0] = make_float4(o[0], o[1], o[2], o[3]);
    dst[1] = make_float4(o[4], o[5], o[6], o[7]);
  }

  // my i-point (computed redundantly per jb-block; ~1% of inner-loop work)
  float pi[8];
  derive_params(p + (size_t)i * NPARAM, pi);
  float ti = pi[0], rai = pi[1], deci = pi[2], psii = pi[3];
  float mci = pi[4], fi = pi[5], di = pi[6];

  __syncthreads();

  float s0 = 0.f, s1 = 0.f, s2 = 0.f, s3 = 0.f,
        s4 = 0.f, s5 = 0.f, s6 = 0.f, s7 = 0.f;

#pragma unroll 8
  for (int j = 0; j < BJ; j++) {
    float4 a0 = ((const float4*)sh)[j * 2];       // t, ra, dec, psi
    float4 a1 = ((const float4*)sh)[j * 2 + 1];   // mc, f, dist, pad
    float dt   = ti - a0.x;
    float dra  = rai - a0.y;
    float ddec = deci - a0.z;
    float dpsi = psii - a0.w;
    s0 += fabsf(dt);
    s1 += sqrtf(dra * dra + ddec * ddec);
    float dmc = mci - a1.x;
    s2 += 30.0f * __builtin_amdgcn_rcpf(30.0f + fabsf(dmc));
    float df = fi - a1.y;
    s3 += __expf(-0.01f * fabsf(df));
    float lo = fminf(di, a1.z);
    float hi = fmaxf(di, a1.z);
    s4 += lo * __builtin_amdgcn_rcpf(hi);
    s5 += fabsf(dpsi);
    s6 += fabsf(dra);
    s7 += fabsf(ddec);
  }

  float* xi = X + (size_t)i * 8;
  atomicAdd(xi + 0, s0); atomicAdd(xi + 1, s1);
  atomicAdd(xi + 2, s2); atomicAdd(xi + 3, s3);
  atomicAdd(xi + 4, s4); atomicAdd(xi + 5, s5);
  atomicAdd(xi + 6, s6); atomicAdd(xi + 7, s7);
}

__global__ __launch_bounds__(64) void mlp_kernel(
    const float* __restrict__ X,
    const float* __restrict__ W1, const float* __restrict__ b1,
    const float* __restrict__ ln_g, const float* __restrict__ ln_b,
    const float* __restrict__ W2, const float* __restrict__ b2,
    float* __restrict__ out) {
  __shared__ float sW1[8 * 32], sW2[32 * 16];
  __shared__ float sb1[32], sg[32], sbb[32], sb2[16];
  int t = threadIdx.x;
  for (int k = t; k < 256; k += 64) sW1[k] = W1[k];
  for (int k = t; k < 512; k += 64) sW2[k] = W2[k];
  if (t < 32) { sb1[t] = b1[t]; sg[t] = ln_g[t]; sbb[t] = ln_b[t]; }
  if (t < 16) sb2[t] = b2[t];
  __syncthreads();

  int i = blockIdx.x * 64 + t;

  const float diag[8] = {0.f, 0.f, 1.f, 1.f, 1.f, 0.f, 0.f, 0.f};
  const float inv_nm1 = 1.0f / (float)(N - 1);
  float x[8];
  const float* Xi = X + (size_t)i * 8;
#pragma unroll
  for (int k = 0; k < 8; k++) x[k] = (Xi[k] - diag[k]) * inv_nm1;

  float h[32];
#pragma unroll
  for (int o = 0; o < 32; o++) {
    float a = sb1[o];
#pragma unroll
    for (int k = 0; k < 8; k++) a += x[k] * sW1[k * 32 + o];
    h[o] = a;
  }

  float mu = 0.f;
#pragma unroll
  for (int o = 0; o < 32; o++) mu += h[o];
  mu *= (1.0f / 32.0f);
  float var = 0.f;
#pragma unroll
  for (int o = 0; o < 32; o++) { float d = h[o] - mu; var += d * d; }
  var *= (1.0f / 32.0f);
  float inv = rsqrtf(var + 1e-5f);

#pragma unroll
  for (int o = 0; o < 32; o++) {
    float hn = (h[o] - mu) * inv * sg[o] + sbb[o];
    h[o] = 0.5f * hn * (1.0f + erff(hn * 0.70710678118654752f));
  }

  float* oi = out + (size_t)i * 16;
#pragma unroll
  for (int o = 0; o < 16; o++) {
    float a = sb2[o];
#pragma unroll
    for (int k = 0; k < 32; k++) a += h[k] * sW2[k * 16 + o];
    oi[o] = a;
  }
}

extern "C" void kernel_launch(void* const* d_in, const int* in_sizes, int n_in,
                              void* d_out, int out_size, void* d_ws, size_t ws_size,
                              hipStream_t stream) {
  const float* p    = (const float*)d_in[0];
  const float* W1   = (const float*)d_in[1];
  const float* b1   = (const float*)d_in[2];
  const float* ln_g = (const float*)d_in[3];
  const float* ln_b = (const float*)d_in[4];
  const float* W2   = (const float*)d_in[5];
  const float* b2   = (const float*)d_in[6];
  float* out = (float*)d_out;
  float* X   = (float*)d_ws;

  hipMemsetAsync(X, 0, (size_t)N * 8 * sizeof(float), stream);
  dim3 grid(N / BI, NJ);
  pairwise_kernel<<<grid, 256, 0, stream>>>(p, X);
  mlp_kernel<<<N / 64, 64, 0, stream>>>(X, W1, b1, ln_g, ln_b, W2, b2, out);
}

// Round 3
// 104.448 us; speedup vs baseline: 1.4552x; 1.4552x over previous
//
#include <hip/hip_runtime.h>
#include <math.h>

#define N       4096
#define NPARAM  15
#define BI      256      // i-rows per block (one per thread)
#define NJP     64       // j-slices, partial-sum path
#define NJA     16       // j-slices, atomic fallback path

__device__ __forceinline__ void derive_params(const float* __restrict__ r, float* o) {
  // r -> (t, ra, dec, psi, mc, f_isco, dist, 0)
  float m1 = r[0] * 95.0f + 5.0f;
  float m2 = r[1] * 95.0f + 5.0f;
  float msum = m1 + m2;
  float mc = expf(0.6f * logf(m1 * m2) - 0.2f * logf(msum));
  o[0] = r[5];
  o[1] = r[3];
  o[2] = r[4];
  o[3] = r[7];
  o[4] = mc;
  o[5] = 220.0f / msum;
  o[6] = r[2] * 2950.0f + 50.0f;
  o[7] = 0.0f;
}

// BJ = j's per slice; PARTIAL: true -> store partial sums to out[jb][i][8],
// false -> atomicAdd into out[i][8] (fallback when ws is too small).
template <int BJ, bool PARTIAL>
__global__ __launch_bounds__(256) void pairwise_kernel(
    const float* __restrict__ p, float* __restrict__ out) {
  __shared__ float sh[BJ * 8];
  int ib = blockIdx.x;
  int jb = blockIdx.y;
  int t  = threadIdx.x;
  int i  = ib * BI + t;

  if (t < BJ) {
    int j = jb * BJ + t;
    float o[8];
    derive_params(p + (size_t)j * NPARAM, o);
    float4* dst = (float4*)(sh + t * 8);
    dst[0] = make_float4(o[0], o[1], o[2], o[3]);
    dst[1] = make_float4(o[4], o[5], o[6], o[7]);
  }

  float pi[8];
  derive_params(p + (size_t)i * NPARAM, pi);
  float ti = pi[0], rai = pi[1], deci = pi[2], psii = pi[3];
  float mci = pi[4], fi = pi[5], di = pi[6];

  __syncthreads();

  float s0 = 0.f, s1 = 0.f, s2 = 0.f, s3 = 0.f,
        s4 = 0.f, s5 = 0.f, s6 = 0.f, s7 = 0.f;

#pragma unroll 8
  for (int j = 0; j < BJ; j++) {
    float4 a0 = ((const float4*)sh)[j * 2];       // t, ra, dec, psi
    float4 a1 = ((const float4*)sh)[j * 2 + 1];   // mc, f, dist, pad
    float dt   = ti - a0.x;
    float dra  = rai - a0.y;
    float ddec = deci - a0.z;
    float dpsi = psii - a0.w;
    s0 += fabsf(dt);
    s1 += sqrtf(dra * dra + ddec * ddec);
    float dmc = mci - a1.x;
    s2 += 30.0f * __builtin_amdgcn_rcpf(30.0f + fabsf(dmc));
    float df = fi - a1.y;
    s3 += __expf(-0.01f * fabsf(df));
    float lo = fminf(di, a1.z);
    float hi = fmaxf(di, a1.z);
    s4 += lo * __builtin_amdgcn_rcpf(hi);
    s5 += fabsf(dpsi);
    s6 += fabsf(dra);
    s7 += fabsf(ddec);
  }

  if (PARTIAL) {
    float* xi = out + ((size_t)jb * N + i) * 8;
    ((float4*)xi)[0] = make_float4(s0, s1, s2, s3);
    ((float4*)xi)[1] = make_float4(s4, s5, s6, s7);
  } else {
    float* xi = out + (size_t)i * 8;
    atomicAdd(xi + 0, s0); atomicAdd(xi + 1, s1);
    atomicAdd(xi + 2, s2); atomicAdd(xi + 3, s3);
    atomicAdd(xi + 4, s4); atomicAdd(xi + 5, s5);
    atomicAdd(xi + 6, s6); atomicAdd(xi + 7, s7);
  }
}

// REDUCE: true -> X is partial[NJP][N][8], sum over slices here.
template <bool REDUCE>
__global__ __launch_bounds__(64) void mlp_kernel(
    const float* __restrict__ X,
    const float* __restrict__ W1, const float* __restrict__ b1,
    const float* __restrict__ ln_g, const float* __restrict__ ln_b,
    const float* __restrict__ W2, const float* __restrict__ b2,
    float* __restrict__ out) {
  __shared__ float sW1[8 * 32], sW2[32 * 16];
  __shared__ float sb1[32], sg[32], sbb[32], sb2[16];
  int t = threadIdx.x;
  for (int k = t; k < 256; k += 64) sW1[k] = W1[k];
  for (int k = t; k < 512; k += 64) sW2[k] = W2[k];
  if (t < 32) { sb1[t] = b1[t]; sg[t] = ln_g[t]; sbb[t] = ln_b[t]; }
  if (t < 16) sb2[t] = b2[t];
  __syncthreads();

  int i = blockIdx.x * 64 + t;

  const float diag[8] = {0.f, 0.f, 1.f, 1.f, 1.f, 0.f, 0.f, 0.f};
  const float inv_nm1 = 1.0f / (float)(N - 1);
  float x[8];
  if (REDUCE) {
#pragma unroll
    for (int k = 0; k < 8; k++) x[k] = 0.f;
#pragma unroll 4
    for (int jb = 0; jb < NJP; jb++) {
      const float4* s = (const float4*)(X + ((size_t)jb * N + i) * 8);
      float4 a = s[0], b = s[1];
      x[0] += a.x; x[1] += a.y; x[2] += a.z; x[3] += a.w;
      x[4] += b.x; x[5] += b.y; x[6] += b.z; x[7] += b.w;
    }
  } else {
    const float4* s = (const float4*)(X + (size_t)i * 8);
    float4 a = s[0], b = s[1];
    x[0] = a.x; x[1] = a.y; x[2] = a.z; x[3] = a.w;
    x[4] = b.x; x[5] = b.y; x[6] = b.z; x[7] = b.w;
  }
#pragma unroll
  for (int k = 0; k < 8; k++) x[k] = (x[k] - diag[k]) * inv_nm1;

  float h[32];
#pragma unroll
  for (int o = 0; o < 32; o++) {
    float a = sb1[o];
#pragma unroll
    for (int k = 0; k < 8; k++) a += x[k] * sW1[k * 32 + o];
    h[o] = a;
  }

  float mu = 0.f;
#pragma unroll
  for (int o = 0; o < 32; o++) mu += h[o];
  mu *= (1.0f / 32.0f);
  float var = 0.f;
#pragma unroll
  for (int o = 0; o < 32; o++) { float d = h[o] - mu; var += d * d; }
  var *= (1.0f / 32.0f);
  float inv = rsqrtf(var + 1e-5f);

#pragma unroll
  for (int o = 0; o < 32; o++) {
    float hn = (h[o] - mu) * inv * sg[o] + sbb[o];
    h[o] = 0.5f * hn * (1.0f + erff(hn * 0.70710678118654752f));
  }

  float* oi = out + (size_t)i * 16;
#pragma unroll
  for (int o = 0; o < 16; o++) {
    float a = sb2[o];
#pragma unroll
    for (int k = 0; k < 32; k++) a += h[k] * sW2[k * 16 + o];
    oi[o] = a;
  }
}

extern "C" void kernel_launch(void* const* d_in, const int* in_sizes, int n_in,
                              void* d_out, int out_size, void* d_ws, size_t ws_size,
                              hipStream_t stream) {
  const float* p    = (const float*)d_in[0];
  const float* W1   = (const float*)d_in[1];
  const float* b1   = (const float*)d_in[2];
  const float* ln_g = (const float*)d_in[3];
  const float* ln_b = (const float*)d_in[4];
  const float* W2   = (const float*)d_in[5];
  const float* b2   = (const float*)d_in[6];
  float* out = (float*)d_out;
  float* ws  = (float*)d_ws;

  const size_t need_partial = (size_t)NJP * N * 8 * sizeof(float);  // 8 MB
  if (ws_size >= need_partial) {
    // split-K with private partial buffers; no atomics, no memset needed
    dim3 grid(N / BI, NJP);
    pairwise_kernel<N / NJP, true><<<grid, 256, 0, stream>>>(p, ws);
    mlp_kernel<true><<<N / 64, 64, 0, stream>>>(ws, W1, b1, ln_g, ln_b, W2, b2, out);
  } else {
    // fallback: atomic accumulation (R1-style, low contention)
    hipMemsetAsync(ws, 0, (size_t)N * 8 * sizeof(float), stream);
    dim3 grid(N / BI, NJA);
    pairwise_kernel<N / NJA, false><<<grid, 256, 0, stream>>>(p, ws);
    mlp_kernel<false><<<N / 64, 64, 0, stream>>>(ws, W1, b1, ln_g, ln_b, W2, b2, out);
  }
}